// Round 1
// baseline (201.742 us; speedup 1.0000x reference)
//
#include <hip/hip_runtime.h>
#include <hip/hip_bf16.h>

// MHA: x[2,2048,1024] f32 in, f32 out. 16 heads x 64, causal.
// Pipeline: convert (1D exact grid) -> FUSED QKV gemm (N=3072, Q pre-scaled
// by 0.125*log2e, V written transposed [1024][4096]) -> flash attention
// (S^T trick, exp2, no-max softmax; v2: UNPAIRED per-q-tile blocks (1024 =
// 4/CU), 64-key k-tiles, K/V double-buffered via counted s_waitcnt vmcnt(4)
// + raw s_barrier so staging overlaps compute) -> proj gemm.

typedef __hip_bfloat16 bf16;
typedef __attribute__((ext_vector_type(8))) short short8;
typedef __attribute__((ext_vector_type(4))) short short4v;
typedef __attribute__((ext_vector_type(4))) float f32x4;

#define MFMA16(a, b, c) __builtin_amdgcn_mfma_f32_16x16x32_bf16((a), (b), (c), 0, 0, 0)

__device__ __forceinline__ void load_lds16(const void* g, void* l) {
  __builtin_amdgcn_global_load_lds(
      (const __attribute__((address_space(1))) void*)g,
      (__attribute__((address_space(3))) void*)l, 16, 0, 0);
}

// Q is pre-scaled by (1/8)*log2(e) so attention can use exp2 directly.
#define QSCALE 0.18033688f

// ---------------- f32 -> bf16 conversion (exact 1D grid: 8192 blocks) --------
__global__ __launch_bounds__(256) void cvt_kernel(
    const float* __restrict__ x, const float* __restrict__ wq,
    const float* __restrict__ wk, const float* __restrict__ wv,
    const float* __restrict__ wo, bf16* __restrict__ xb,
    bf16* __restrict__ wcat) {
  const int bx = blockIdx.x;
  const float* src;
  bf16* dst;
  int ib;
  if (bx < 4096) { src = x; dst = xb; ib = bx; }
  else {
    const int wseg = (bx - 4096) >> 10;
    ib = (bx - 4096) & 1023;
    src = wseg == 0 ? wq : wseg == 1 ? wk : wseg == 2 ? wv : wo;
    dst = wcat + (size_t)wseg * 1048576;
  }
  const int i = (ib * 256 + threadIdx.x) * 4;
  const float4 v = *(const float4*)(src + i);
  short4v p;
  *(__hip_bfloat162*)&p = __float22bfloat162_rn(float2{v.x, v.y});
  *((__hip_bfloat162*)&p + 1) = __float22bfloat162_rn(float2{v.z, v.w});
  *(short4v*)(dst + i) = p;
}

// ---------------- Fused QKV GEMM: [4096,1024] @ [3072,1024]^T ----------------
// 128x128 tile, BK=64, 4 waves 2x2. grid (24, 32) = 768 blocks = 3/CU.
__global__ __launch_bounds__(256) void qkv_kernel(
    const bf16* __restrict__ x, const bf16* __restrict__ Wcat,
    const float* __restrict__ bq, const float* __restrict__ bk,
    const float* __restrict__ bv, bf16* __restrict__ Qb,
    bf16* __restrict__ Kb, bf16* __restrict__ Vtg) {
  constexpr int K = 1024;
  __shared__ bf16 As[128 * 64];
  __shared__ bf16 Bs[128 * 64];
  const int t = threadIdx.x;
  const int lane = t & 63, w = t >> 6;
  const int quad = lane >> 4, r = lane & 15;
  const int m0 = blockIdx.y * 128;
  const int ncol = blockIdx.x * 128;        // 0..2944
  const int seg = ncol >> 10;               // 0=Q, 1=K, 2=V
  const int n0 = ncol & 1023;
  const int wm = w >> 1, wn = w & 1;

  f32x4 acc[4][4] = {};

  for (int k0 = 0; k0 < K; k0 += 64) {
    __syncthreads();
#pragma unroll
    for (int p = 0; p < 4; ++p) {           // A: 1024 chunks
      const int c = p * 256 + w * 64 + lane;
      const int row = c >> 3;
      const int scb = (c & 7) ^ (row & 7);
      load_lds16(x + (size_t)(m0 + row) * K + k0 + scb * 8, As + c * 8);
    }
#pragma unroll
    for (int p = 0; p < 4; ++p) {           // B: 1024 chunks
      const int c = p * 256 + w * 64 + lane;
      const int row = c >> 3;
      const int scb = (c & 7) ^ (row & 7);
      load_lds16(Wcat + (size_t)(ncol + row) * K + k0 + scb * 8, Bs + c * 8);
    }
    __syncthreads();
    short8 af[4][2], bfr[4][2];
#pragma unroll
    for (int ks = 0; ks < 2; ++ks) {
#pragma unroll
      for (int i = 0; i < 4; ++i) {
        const int ra = wm * 64 + i * 16 + r;
        af[i][ks] = *(const short8*)(As + ra * 64 +
                                     (((ks * 4 + quad) ^ (ra & 7)) * 8));
        const int rb = wn * 64 + i * 16 + r;
        bfr[i][ks] = *(const short8*)(Bs + rb * 64 +
                                      (((ks * 4 + quad) ^ (rb & 7)) * 8));
      }
    }
#pragma unroll
    for (int ks = 0; ks < 2; ++ks)
#pragma unroll
      for (int i = 0; i < 4; ++i)
#pragma unroll
        for (int j = 0; j < 4; ++j)
          acc[i][j] = MFMA16(af[i][ks], bfr[j][ks], acc[i][j]);
  }

  const float* bias = seg == 0 ? bq : seg == 1 ? bk : bv;
  const float scale = seg == 0 ? QSCALE : 1.0f;
  bf16* dst01 = seg == 0 ? Qb : Kb;
#pragma unroll
  for (int i = 0; i < 4; ++i) {
    const int m = m0 + wm * 64 + i * 16 + quad * 4;
#pragma unroll
    for (int j = 0; j < 4; ++j) {
      const int nn = n0 + wn * 64 + j * 16 + r;
      const float bv_ = bias[nn];
      if (seg == 2) {                       // V: transposed packed store
        short4v pk;
        *(__hip_bfloat162*)&pk = __float22bfloat162_rn(
            float2{acc[i][j][0] + bv_, acc[i][j][1] + bv_});
        *((__hip_bfloat162*)&pk + 1) = __float22bfloat162_rn(
            float2{acc[i][j][2] + bv_, acc[i][j][3] + bv_});
        *(short4v*)(Vtg + (size_t)nn * 4096 + m) = pk;
      } else {
#pragma unroll
        for (int g = 0; g < 4; ++g)
          dst01[(size_t)(m + g) * 1024 + nn] =
              __float2bfloat16((acc[i][j][g] + bv_) * scale);
      }
    }
  }
}

// ---------------- proj GEMM: out[4096,1024] = Ob @ Wo^T + bo (f32 out) -------
__global__ __launch_bounds__(256) void proj_kernel(const bf16* __restrict__ X,
                                                   const bf16* __restrict__ W,
                                                   const float* __restrict__ bias,
                                                   float* __restrict__ Y) {
  constexpr int K = 1024, N = 1024;
  __shared__ bf16 As[64 * 64];
  __shared__ bf16 Bs[128 * 64];
  const int t = threadIdx.x;
  const int lane = t & 63, w = t >> 6;
  const int quad = lane >> 4, r = lane & 15;
  const int m0 = blockIdx.y * 64, n0 = blockIdx.x * 128;
  const int wm = w >> 1, wn = w & 1;

  f32x4 acc[2][4] = {};

  for (int k0 = 0; k0 < K; k0 += 64) {
    __syncthreads();
#pragma unroll
    for (int p = 0; p < 2; ++p) {           // A: 512 chunks
      const int c = p * 256 + w * 64 + lane;
      const int row = c >> 3;
      const int scb = (c & 7) ^ (row & 7);
      load_lds16(X + (size_t)(m0 + row) * K + k0 + scb * 8, As + c * 8);
    }
#pragma unroll
    for (int p = 0; p < 4; ++p) {           // B: 1024 chunks
      const int c = p * 256 + w * 64 + lane;
      const int row = c >> 3;
      const int scb = (c & 7) ^ (row & 7);
      load_lds16(W + (size_t)(n0 + row) * K + k0 + scb * 8, Bs + c * 8);
    }
    __syncthreads();
    short8 af[2][2], bfr[4][2];
#pragma unroll
    for (int ks = 0; ks < 2; ++ks) {
#pragma unroll
      for (int i = 0; i < 2; ++i) {
        const int ra = wm * 32 + i * 16 + r;
        af[i][ks] = *(const short8*)(As + ra * 64 +
                                     (((ks * 4 + quad) ^ (ra & 7)) * 8));
      }
#pragma unroll
      for (int j = 0; j < 4; ++j) {
        const int rb = wn * 64 + j * 16 + r;
        bfr[j][ks] = *(const short8*)(Bs + rb * 64 +
                                      (((ks * 4 + quad) ^ (rb & 7)) * 8));
      }
    }
#pragma unroll
    for (int ks = 0; ks < 2; ++ks)
#pragma unroll
      for (int i = 0; i < 2; ++i)
#pragma unroll
        for (int j = 0; j < 4; ++j)
          acc[i][j] = MFMA16(af[i][ks], bfr[j][ks], acc[i][j]);
  }
#pragma unroll
  for (int i = 0; i < 2; ++i) {
    const int m = m0 + wm * 32 + i * 16 + quad * 4;
#pragma unroll
    for (int j = 0; j < 4; ++j) {
      const int n = n0 + wn * 64 + j * 16 + r;
      const float bv = bias[n];
#pragma unroll
      for (int g = 0; g < 4; ++g)
        Y[(size_t)(m + g) * N + n] = acc[i][j][g] + bv;
    }
  }
}

// ---------------- Flash attention v2 (unpaired, dbuf, counted vmcnt) ---------
// One block per 64-row q-tile: grid (32,16,2) = 1024 blocks = 4/CU (LDS 40KB,
// VGPR<=128 via launch_bounds(256,4)). j = 31-bx launches longest blocks
// first. 64-key k-tiles, K/V double-buffered: each wave issues the next
// tile's 4 global_load_lds, then s_waitcnt vmcnt(4) (previous tile's loads
// done) + raw s_barrier -- staging latency hides under compute; vmcnt never
// drains to 0 in the main loop. S^T = K*Q^T; no-max softmax (raw exp2;
// masked -> exp2(-1e30)=0); per-q denominators reduced once at the end.
__global__ __launch_bounds__(256, 4) void attn_kernel(const bf16* __restrict__ Qb,
                                                      const bf16* __restrict__ Kb,
                                                      const bf16* __restrict__ Vtg,
                                                      bf16* __restrict__ Ob) {
  const int j = 31 - blockIdx.x;            // longest-first for tail balance
  const int h = blockIdx.y, b = blockIdx.z;
  const int t = threadIdx.x;
  const int lane = t & 63, w = t >> 6;
  const int quad = lane >> 4, r = lane & 15;

  __shared__ bf16 Ks[2][64 * 64];   // (key, d)  rows 128B, XOR-8 swizzled
  __shared__ bf16 Vt[2][64 * 64];   // (d, key)  rows 128B, XOR-8 swizzled
  __shared__ bf16 Pl[4][16 * 64];   // per-wave P, rows 128B, XOR-8 (16B gran)

  const int nkt = j + 1;
  const int qrow = j * 64 + w * 16 + r;

  // Q fragments (B-operand), issued first so they overlap staging.
  short8 qf[2];
#pragma unroll
  for (int ks = 0; ks < 2; ++ks)
    qf[ks] = *(const short8*)(Qb + (size_t)(b * 2048 + qrow) * 1024 +
                              h * 64 + ks * 32 + quad * 8);

  // per-thread staging geometry (2 chunks each for K and V per tile)
  const bf16 *kg[2], *vg[2];
  int lofs[2];
#pragma unroll
  for (int p = 0; p < 2; ++p) {
    const int c = p * 256 + t;
    const int row = c >> 3, scb = (c & 7) ^ (row & 7);
    kg[p] = Kb + (size_t)(b * 2048 + row) * 1024 + h * 64 + scb * 8;
    vg[p] = Vtg + (size_t)(h * 64 + row) * 4096 + b * 2048 + scb * 8;
    lofs[p] = c * 8;
  }

  auto stage = [&](int kt, int bs) {
#pragma unroll
    for (int p = 0; p < 2; ++p)
      load_lds16(kg[p] + (size_t)kt * 65536, &Ks[bs][lofs[p]]);
#pragma unroll
    for (int p = 0; p < 2; ++p)
      load_lds16(vg[p] + (size_t)kt * 64, &Vt[bs][lofs[p]]);
  };

  f32x4 o[4] = {};
  float lsum = 0.f;
  bf16* const plw = Pl[w];

  auto compute = [&](int kt, int bs, bool mask) {
    const bf16* const ksb = Ks[bs];
    const bf16* const vtb = Vt[bs];
    // ---- S^T = K * Q^T ----
    f32x4 st[4] = {};
#pragma unroll
    for (int ks = 0; ks < 2; ++ks) {
      short8 kf[4];
#pragma unroll
      for (int mt = 0; mt < 4; ++mt) {
        const int key = mt * 16 + r;
        kf[mt] = *(const short8*)(ksb + key * 64 +
                                  (((ks * 4 + quad) ^ (key & 7)) * 8));
      }
#pragma unroll
      for (int mt = 0; mt < 4; ++mt) st[mt] = MFMA16(kf[mt], qf[ks], st[mt]);
    }
    if (mask) {
#pragma unroll
      for (int mt = 0; mt < 4; ++mt)
#pragma unroll
        for (int g = 0; g < 4; ++g) {
          const int key = kt * 64 + mt * 16 + quad * 4 + g;
          if (key > qrow) st[mt][g] = -1e30f;
        }
    }
    // ---- softmax numerators + P write (wave-local buffer) ----
#pragma unroll
    for (int mt = 0; mt < 4; ++mt) {
      const float p0 = exp2f(st[mt][0]), p1 = exp2f(st[mt][1]);
      const float p2 = exp2f(st[mt][2]), p3 = exp2f(st[mt][3]);
      lsum += (p0 + p1) + (p2 + p3);
      short4v pk;
      *(__hip_bfloat162*)&pk = __float22bfloat162_rn(float2{p0, p1});
      *((__hip_bfloat162*)&pk + 1) = __float22bfloat162_rn(float2{p2, p3});
      const int key8 = mt * 2 + (quad >> 1);
      *(short4v*)(plw + r * 64 + ((key8 ^ (r & 7)) * 8) + (quad & 1) * 4) = pk;
    }
    // wave-local fence: our Pl writes must land before our Pl reads
    asm volatile("s_waitcnt lgkmcnt(0)" ::: "memory");
    // ---- PV: O^T += V^T * P^T ----
#pragma unroll
    for (int ks = 0; ks < 2; ++ks) {
      short8 vf[4];
#pragma unroll
      for (int mt = 0; mt < 4; ++mt) {
        const int d = mt * 16 + r;
        vf[mt] = *(const short8*)(vtb + d * 64 +
                                  (((ks * 4 + quad) ^ (d & 7)) * 8));
      }
      const short8 pf =
          *(const short8*)(plw + r * 64 + (((ks * 4 + quad) ^ (r & 7)) * 8));
#pragma unroll
      for (int mt = 0; mt < 4; ++mt) o[mt] = MFMA16(vf[mt], pf, o[mt]);
    }
  };

  stage(0, 0);
  int kt = 0;
  for (; kt < nkt - 1; ++kt) {
    stage(kt + 1, (kt + 1) & 1);            // prefetch next tile
    asm volatile("s_waitcnt vmcnt(4)" ::: "memory");  // tile kt landed
    __builtin_amdgcn_s_barrier();
    __builtin_amdgcn_sched_barrier(0);
    compute(kt, kt & 1, false);
    __builtin_amdgcn_sched_barrier(0);
    __builtin_amdgcn_s_barrier();           // buf (kt+1)&1^1 free for restage
  }
  asm volatile("s_waitcnt vmcnt(0)" ::: "memory");
  __builtin_amdgcn_s_barrier();
  __builtin_amdgcn_sched_barrier(0);
  compute(kt, kt & 1, true);                // last tile: diagonal mask

  // denominators: combine the 4 quads' partial sums
  lsum += __shfl_xor(lsum, 16);
  lsum += __shfl_xor(lsum, 32);
  const float inv = 1.f / lsum;

  // epilogue: O^T[d][q] -> Ob[b, q, h*64+d]; 4 consecutive d -> 8B store
#pragma unroll
  for (int mt = 0; mt < 4; ++mt) {
    const int d0 = mt * 16 + quad * 4;
    short4v ph;
    *(__hip_bfloat162*)&ph = __float22bfloat162_rn(
        float2{o[mt][0] * inv, o[mt][1] * inv});
    *((__hip_bfloat162*)&ph + 1) = __float22bfloat162_rn(
        float2{o[mt][2] * inv, o[mt][3] * inv});
    *(short4v*)(Ob + (size_t)(b * 2048 + qrow) * 1024 + h * 64 + d0) = ph;
  }
}

extern "C" void kernel_launch(void* const* d_in, const int* in_sizes, int n_in,
                              void* d_out, int out_size, void* d_ws, size_t ws_size,
                              hipStream_t stream) {
  const float* x  = (const float*)d_in[0];
  const float* Wq = (const float*)d_in[1];
  const float* bq = (const float*)d_in[2];
  const float* Wk = (const float*)d_in[3];
  const float* bk = (const float*)d_in[4];
  const float* Wv = (const float*)d_in[5];
  const float* bv = (const float*)d_in[6];
  const float* Wo = (const float*)d_in[7];
  const float* bo = (const float*)d_in[8];
  float* out = (float*)d_out;

  bf16* xb   = (bf16*)d_ws;                     // 4M
  bf16* wcat = xb + (size_t)4096 * 1024;        // 4M: [wq|wk|wv|wo]
  bf16* wob  = wcat + (size_t)3 * 1024 * 1024;
  bf16* Qb   = wcat + (size_t)4 * 1024 * 1024;  // 4M each
  bf16* Kb   = Qb  + (size_t)4096 * 1024;
  bf16* Vtg  = Kb  + (size_t)4096 * 1024;       // V^T [1024][4096]
  bf16* Ob   = Vtg + (size_t)4096 * 1024;
  const size_t need = ((size_t)4096 * 1024 * 5 + (size_t)1024 * 1024 * 4) * 2;
  if (ws_size < need) return;

  cvt_kernel<<<8192, 256, 0, stream>>>(x, Wq, Wk, Wv, Wo, xb, wcat);
  qkv_kernel<<<dim3(24, 32), 256, 0, stream>>>(xb, wcat, bq, bk, bv,
                                               Qb, Kb, Vtg);
  attn_kernel<<<dim3(32, 16, 2), 256, 0, stream>>>(Qb, Kb, Vtg, Ob);
  proj_kernel<<<dim3(8, 64), 256, 0, stream>>>(Ob, wob, bo, out);
}

// Round 2
// 182.868 us; speedup vs baseline: 1.1032x; 1.1032x over previous
//
#include <hip/hip_runtime.h>
#include <hip/hip_bf16.h>

// MHA: x[2,2048,1024] f32 in, f32 out. 16 heads x 64, causal.
// Pipeline: convert -> FUSED QKV gemm (Q pre-scaled, V transposed) ->
// flash attention v3: paired q-tiles (jlo=pair, jhi=31-pair, balanced 33
// 64-key tiles/block), 8-wave blocks, wave-group k-split (group A even
// tiles, group B odd tiles; additive no-max softmax => partial O/lsum just
// sum), K/V 4-buffered with counted vmcnt, XCD-swizzled 1-D grid
// -> proj gemm.

typedef __hip_bfloat16 bf16;
typedef __attribute__((ext_vector_type(8))) short short8;
typedef __attribute__((ext_vector_type(4))) short short4v;
typedef __attribute__((ext_vector_type(4))) float f32x4;

#define MFMA16(a, b, c) __builtin_amdgcn_mfma_f32_16x16x32_bf16((a), (b), (c), 0, 0, 0)

__device__ __forceinline__ void load_lds16(const void* g, void* l) {
  __builtin_amdgcn_global_load_lds(
      (const __attribute__((address_space(1))) void*)g,
      (__attribute__((address_space(3))) void*)l, 16, 0, 0);
}

// Q is pre-scaled by (1/8)*log2(e) so attention can use exp2 directly.
#define QSCALE 0.18033688f

// ---------------- f32 -> bf16 conversion (exact 1D grid: 8192 blocks) --------
__global__ __launch_bounds__(256) void cvt_kernel(
    const float* __restrict__ x, const float* __restrict__ wq,
    const float* __restrict__ wk, const float* __restrict__ wv,
    const float* __restrict__ wo, bf16* __restrict__ xb,
    bf16* __restrict__ wcat) {
  const int bx = blockIdx.x;
  const float* src;
  bf16* dst;
  int ib;
  if (bx < 4096) { src = x; dst = xb; ib = bx; }
  else {
    const int wseg = (bx - 4096) >> 10;
    ib = (bx - 4096) & 1023;
    src = wseg == 0 ? wq : wseg == 1 ? wk : wseg == 2 ? wv : wo;
    dst = wcat + (size_t)wseg * 1048576;
  }
  const int i = (ib * 256 + threadIdx.x) * 4;
  const float4 v = *(const float4*)(src + i);
  short4v p;
  *(__hip_bfloat162*)&p = __float22bfloat162_rn(float2{v.x, v.y});
  *((__hip_bfloat162*)&p + 1) = __float22bfloat162_rn(float2{v.z, v.w});
  *(short4v*)(dst + i) = p;
}

// ---------------- Fused QKV GEMM: [4096,1024] @ [3072,1024]^T ----------------
__global__ __launch_bounds__(256) void qkv_kernel(
    const bf16* __restrict__ x, const bf16* __restrict__ Wcat,
    const float* __restrict__ bq, const float* __restrict__ bk,
    const float* __restrict__ bv, bf16* __restrict__ Qb,
    bf16* __restrict__ Kb, bf16* __restrict__ Vtg) {
  constexpr int K = 1024;
  __shared__ bf16 As[128 * 64];
  __shared__ bf16 Bs[128 * 64];
  const int t = threadIdx.x;
  const int lane = t & 63, w = t >> 6;
  const int quad = lane >> 4, r = lane & 15;
  const int m0 = blockIdx.y * 128;
  const int ncol = blockIdx.x * 128;        // 0..2944
  const int seg = ncol >> 10;               // 0=Q, 1=K, 2=V
  const int n0 = ncol & 1023;
  const int wm = w >> 1, wn = w & 1;

  f32x4 acc[4][4] = {};

  for (int k0 = 0; k0 < K; k0 += 64) {
    __syncthreads();
#pragma unroll
    for (int p = 0; p < 4; ++p) {           // A: 1024 chunks
      const int c = p * 256 + w * 64 + lane;
      const int row = c >> 3;
      const int scb = (c & 7) ^ (row & 7);
      load_lds16(x + (size_t)(m0 + row) * K + k0 + scb * 8, As + c * 8);
    }
#pragma unroll
    for (int p = 0; p < 4; ++p) {           // B: 1024 chunks
      const int c = p * 256 + w * 64 + lane;
      const int row = c >> 3;
      const int scb = (c & 7) ^ (row & 7);
      load_lds16(Wcat + (size_t)(ncol + row) * K + k0 + scb * 8, Bs + c * 8);
    }
    __syncthreads();
    short8 af[4][2], bfr[4][2];
#pragma unroll
    for (int ks = 0; ks < 2; ++ks) {
#pragma unroll
      for (int i = 0; i < 4; ++i) {
        const int ra = wm * 64 + i * 16 + r;
        af[i][ks] = *(const short8*)(As + ra * 64 +
                                     (((ks * 4 + quad) ^ (ra & 7)) * 8));
        const int rb = wn * 64 + i * 16 + r;
        bfr[i][ks] = *(const short8*)(Bs + rb * 64 +
                                      (((ks * 4 + quad) ^ (rb & 7)) * 8));
      }
    }
#pragma unroll
    for (int ks = 0; ks < 2; ++ks)
#pragma unroll
      for (int i = 0; i < 4; ++i)
#pragma unroll
        for (int j = 0; j < 4; ++j)
          acc[i][j] = MFMA16(af[i][ks], bfr[j][ks], acc[i][j]);
  }

  const float* bias = seg == 0 ? bq : seg == 1 ? bk : bv;
  const float scale = seg == 0 ? QSCALE : 1.0f;
  bf16* dst01 = seg == 0 ? Qb : Kb;
#pragma unroll
  for (int i = 0; i < 4; ++i) {
    const int m = m0 + wm * 64 + i * 16 + quad * 4;
#pragma unroll
    for (int j = 0; j < 4; ++j) {
      const int nn = n0 + wn * 64 + j * 16 + r;
      const float bv_ = bias[nn];
      if (seg == 2) {                       // V: transposed packed store
        short4v pk;
        *(__hip_bfloat162*)&pk = __float22bfloat162_rn(
            float2{acc[i][j][0] + bv_, acc[i][j][1] + bv_});
        *((__hip_bfloat162*)&pk + 1) = __float22bfloat162_rn(
            float2{acc[i][j][2] + bv_, acc[i][j][3] + bv_});
        *(short4v*)(Vtg + (size_t)nn * 4096 + m) = pk;
      } else {
#pragma unroll
        for (int g = 0; g < 4; ++g)
          dst01[(size_t)(m + g) * 1024 + nn] =
              __float2bfloat16((acc[i][j][g] + bv_) * scale);
      }
    }
  }
}

// ---------------- proj GEMM: out[4096,1024] = Ob @ Wo^T + bo (f32 out) -------
__global__ __launch_bounds__(256) void proj_kernel(const bf16* __restrict__ X,
                                                   const bf16* __restrict__ W,
                                                   const float* __restrict__ bias,
                                                   float* __restrict__ Y) {
  constexpr int K = 1024, N = 1024;
  __shared__ bf16 As[64 * 64];
  __shared__ bf16 Bs[128 * 64];
  const int t = threadIdx.x;
  const int lane = t & 63, w = t >> 6;
  const int quad = lane >> 4, r = lane & 15;
  const int m0 = blockIdx.y * 64, n0 = blockIdx.x * 128;
  const int wm = w >> 1, wn = w & 1;

  f32x4 acc[2][4] = {};

  for (int k0 = 0; k0 < K; k0 += 64) {
    __syncthreads();
#pragma unroll
    for (int p = 0; p < 2; ++p) {           // A: 512 chunks
      const int c = p * 256 + w * 64 + lane;
      const int row = c >> 3;
      const int scb = (c & 7) ^ (row & 7);
      load_lds16(X + (size_t)(m0 + row) * K + k0 + scb * 8, As + c * 8);
    }
#pragma unroll
    for (int p = 0; p < 4; ++p) {           // B: 1024 chunks
      const int c = p * 256 + w * 64 + lane;
      const int row = c >> 3;
      const int scb = (c & 7) ^ (row & 7);
      load_lds16(W + (size_t)(n0 + row) * K + k0 + scb * 8, Bs + c * 8);
    }
    __syncthreads();
    short8 af[2][2], bfr[4][2];
#pragma unroll
    for (int ks = 0; ks < 2; ++ks) {
#pragma unroll
      for (int i = 0; i < 2; ++i) {
        const int ra = wm * 32 + i * 16 + r;
        af[i][ks] = *(const short8*)(As + ra * 64 +
                                     (((ks * 4 + quad) ^ (ra & 7)) * 8));
      }
#pragma unroll
      for (int j = 0; j < 4; ++j) {
        const int rb = wn * 64 + j * 16 + r;
        bfr[j][ks] = *(const short8*)(Bs + rb * 64 +
                                      (((ks * 4 + quad) ^ (rb & 7)) * 8));
      }
    }
#pragma unroll
    for (int ks = 0; ks < 2; ++ks)
#pragma unroll
      for (int i = 0; i < 2; ++i)
#pragma unroll
        for (int j = 0; j < 4; ++j)
          acc[i][j] = MFMA16(af[i][ks], bfr[j][ks], acc[i][j]);
  }
#pragma unroll
  for (int i = 0; i < 2; ++i) {
    const int m = m0 + wm * 32 + i * 16 + quad * 4;
#pragma unroll
    for (int j = 0; j < 4; ++j) {
      const int n = n0 + wn * 64 + j * 16 + r;
      const float bv = bias[n];
#pragma unroll
      for (int g = 0; g < 4; ++g)
        Y[(size_t)(m + g) * N + n] = acc[i][j][g] + bv;
    }
  }
}

// ---------------- Flash attention v3: paired + 8-wave group k-split ----------
// grid = 512 (1-D, XCD-swizzled decode), 512 threads (8 waves).
// pair p: jlo=p, jhi=31-p; every block = 33 64-key tiles total (balanced).
// Wave-group g = w>>2: group 0 computes even k-tiles, group 1 odd k-tiles,
// each for BOTH q-tiles (kf/vf fragment reads shared between q-tiles).
// No-max softmax => partial O / lsum are additive; groups combined via LDS
// at the end. K/V 4-buffered (2 halves x 2 tiles); per iteration stage the
// next 2 tiles then s_waitcnt vmcnt(n_issued) -- never drains in-loop.
__global__ __launch_bounds__(512, 4) void attn_kernel(const bf16* __restrict__ Qb,
                                                      const bf16* __restrict__ Kb,
                                                      const bf16* __restrict__ Vtg,
                                                      bf16* __restrict__ Ob) {
  // XCD-swizzled decode: n = gl + 8*pair + 128*gh; g=(h,b) index = gl+8*gh.
  // All 16 pair-blocks of one (h,b) share n%8 -> same XCD L2 holds its K/V.
  const int n = blockIdx.x;
  const int gl = n & 7, pair = (n >> 3) & 15, gh = n >> 7;
  const int g = gl + 8 * gh;                // 0..31
  const int h = g & 15, b = g >> 4;
  const int t = threadIdx.x;
  const int lane = t & 63, w = t >> 6;
  const int grp = w >> 2, ww = w & 3;
  const int quad = lane >> 4, r = lane & 15;

  __shared__ __align__(16) bf16 Ks[2][2][64 * 64];  // [half][sub][key,d] 32K
  __shared__ __align__(16) bf16 Vt[2][2][64 * 64];  // [half][sub][d,key] 32K
  __shared__ __align__(16) bf16 Pl[8][16 * 64];     // per-wave P, 16K

  const int jlo = pair, jhi = 31 - pair;
  const int NL = jlo + 1, T = jhi + 1;      // k-tile counts (NL<=16<17<=T)
  const int nit = (T + 1) >> 1;
  const int qrow_lo = jlo * 64 + ww * 16 + r;
  const int qrow_hi = jhi * 64 + ww * 16 + r;

  // Q fragments for both q-tiles (B-operand)
  short8 qfh[2], qfl[2];
#pragma unroll
  for (int ks = 0; ks < 2; ++ks) {
    qfh[ks] = *(const short8*)(Qb + (size_t)(b * 2048 + qrow_hi) * 1024 +
                               h * 64 + ks * 32 + quad * 8);
    qfl[ks] = *(const short8*)(Qb + (size_t)(b * 2048 + qrow_lo) * 1024 +
                               h * 64 + ks * 32 + quad * 8);
  }

  // staging geometry: 512 threads, 1 chunk per tile per array per thread
  const int c = t;
  const int row = c >> 3, scb = (c & 7) ^ (row & 7);
  const bf16* const kg = Kb + (size_t)(b * 2048 + row) * 1024 + h * 64 + scb * 8;
  const bf16* const vg = Vtg + (size_t)(h * 64 + row) * 4096 +
                         (size_t)b * 2048 + scb * 8;

  auto stage = [&](int tile, int half, int sub) {
    load_lds16(kg + (size_t)tile * 65536, &Ks[half][sub][c * 8]);
    load_lds16(vg + tile * 64, &Vt[half][sub][c * 8]);
  };

  f32x4 oh[4] = {}, ol[4] = {};
  float lsh = 0.f, lsl = 0.f;
  bf16* const plw = Pl[w];

  auto compute = [&](int kt, int half, int sub) {
    const bf16* const ksb = Ks[half][sub];
    const bf16* const vtb = Vt[half][sub];
    const bool lo = (kt < NL);
    // ---- S^T both q-tiles, kf shared ----
    f32x4 sh[4] = {}, sl[4] = {};
#pragma unroll
    for (int ks = 0; ks < 2; ++ks) {
      short8 kf[4];
#pragma unroll
      for (int mt = 0; mt < 4; ++mt)
        kf[mt] = *(const short8*)(ksb + (mt * 16 + r) * 64 +
                                  (((ks * 4 + quad) ^ (r & 7)) * 8));
#pragma unroll
      for (int mt = 0; mt < 4; ++mt) sh[mt] = MFMA16(kf[mt], qfh[ks], sh[mt]);
      if (lo) {
#pragma unroll
        for (int mt = 0; mt < 4; ++mt) sl[mt] = MFMA16(kf[mt], qfl[ks], sl[mt]);
      }
    }
    // ---- hi: mask/exp/pack -> LDS P ----
    if (kt == T - 1) {
#pragma unroll
      for (int mt = 0; mt < 4; ++mt)
#pragma unroll
        for (int g4 = 0; g4 < 4; ++g4) {
          const int key = kt * 64 + mt * 16 + quad * 4 + g4;
          if (key > qrow_hi) sh[mt][g4] = -1e30f;
        }
    }
#pragma unroll
    for (int mt = 0; mt < 4; ++mt) {
      const float p0 = exp2f(sh[mt][0]), p1 = exp2f(sh[mt][1]);
      const float p2 = exp2f(sh[mt][2]), p3 = exp2f(sh[mt][3]);
      lsh += (p0 + p1) + (p2 + p3);
      short4v pk;
      *(__hip_bfloat162*)&pk = __float22bfloat162_rn(float2{p0, p1});
      *((__hip_bfloat162*)&pk + 1) = __float22bfloat162_rn(float2{p2, p3});
      const int key8 = mt * 2 + (quad >> 1);
      *(short4v*)(plw + r * 64 + ((key8 ^ (r & 7)) * 8) + (quad & 1) * 4) = pk;
    }
    // ---- lo: mask/exp/pack into registers (written to P after PV-hi) ----
    short4v pkl[4];
    if (lo) {
      if (kt == NL - 1) {
#pragma unroll
        for (int mt = 0; mt < 4; ++mt)
#pragma unroll
          for (int g4 = 0; g4 < 4; ++g4) {
            const int key = kt * 64 + mt * 16 + quad * 4 + g4;
            if (key > qrow_lo) sl[mt][g4] = -1e30f;
          }
      }
#pragma unroll
      for (int mt = 0; mt < 4; ++mt) {
        const float p0 = exp2f(sl[mt][0]), p1 = exp2f(sl[mt][1]);
        const float p2 = exp2f(sl[mt][2]), p3 = exp2f(sl[mt][3]);
        lsl += (p0 + p1) + (p2 + p3);
        *(__hip_bfloat162*)&pkl[mt] = __float22bfloat162_rn(float2{p0, p1});
        *((__hip_bfloat162*)&pkl[mt] + 1) =
            __float22bfloat162_rn(float2{p2, p3});
      }
    }
    asm volatile("s_waitcnt lgkmcnt(0)" ::: "memory");  // P-hi writes landed
    // ---- PV hi, vf cached for lo ----
    short8 vf[2][4];
#pragma unroll
    for (int ks = 0; ks < 2; ++ks) {
#pragma unroll
      for (int mt = 0; mt < 4; ++mt)
        vf[ks][mt] = *(const short8*)(vtb + (mt * 16 + r) * 64 +
                                      (((ks * 4 + quad) ^ (r & 7)) * 8));
      const short8 pf =
          *(const short8*)(plw + r * 64 + (((ks * 4 + quad) ^ (r & 7)) * 8));
#pragma unroll
      for (int mt = 0; mt < 4; ++mt) oh[mt] = MFMA16(vf[ks][mt], pf, oh[mt]);
    }
    if (lo) {
      // overwrite P with lo (in-order per-wave DS: prior pf reads already
      // captured their data)
#pragma unroll
      for (int mt = 0; mt < 4; ++mt) {
        const int key8 = mt * 2 + (quad >> 1);
        *(short4v*)(plw + r * 64 + ((key8 ^ (r & 7)) * 8) + (quad & 1) * 4) =
            pkl[mt];
      }
      asm volatile("s_waitcnt lgkmcnt(0)" ::: "memory");
#pragma unroll
      for (int ks = 0; ks < 2; ++ks) {
        const short8 pf =
            *(const short8*)(plw + r * 64 + (((ks * 4 + quad) ^ (r & 7)) * 8));
#pragma unroll
        for (int mt = 0; mt < 4; ++mt) ol[mt] = MFMA16(vf[ks][mt], pf, ol[mt]);
      }
    }
  };

  // prologue: tiles 0,1 -> half 0 (T >= 17, both always exist)
  stage(0, 0, 0);
  stage(1, 0, 1);
  for (int i = 0; i < nit; ++i) {
    const int half = i & 1, nhalf = half ^ 1;
    const int t2 = 2 * i + 2, t3 = 2 * i + 3;
    int nis = 0;
    if (t2 < T) { stage(t2, nhalf, 0); nis += 2; }
    if (t3 < T) { stage(t3, nhalf, 1); nis += 2; }
    if (nis == 4)      asm volatile("s_waitcnt vmcnt(4)" ::: "memory");
    else if (nis == 2) asm volatile("s_waitcnt vmcnt(2)" ::: "memory");
    else               asm volatile("s_waitcnt vmcnt(0)" ::: "memory");
    __builtin_amdgcn_s_barrier();
    __builtin_amdgcn_sched_barrier(0);
    const int myt = 2 * i + grp;
    if (myt < T) compute(myt, half, grp);
    __builtin_amdgcn_sched_barrier(0);
    __builtin_amdgcn_s_barrier();
  }

  // ---- cross-group combine (additive no-max softmax) ----
  __syncthreads();
  f32x4* const cb = (f32x4*)&Ks[0][0][0];   // 32 KB: [ww][qi][mt][lane]
  float* const lb = (float*)&Vt[0][0][0];   // 2 KB:  [ww*2+qi][lane]
  if (grp == 1) {
#pragma unroll
    for (int mt = 0; mt < 4; ++mt) {
      cb[((ww * 2 + 0) * 4 + mt) * 64 + lane] = oh[mt];
      cb[((ww * 2 + 1) * 4 + mt) * 64 + lane] = ol[mt];
    }
    lb[(ww * 2 + 0) * 64 + lane] = lsh;
    lb[(ww * 2 + 1) * 64 + lane] = lsl;
  }
  __syncthreads();
  if (grp == 0) {
#pragma unroll
    for (int mt = 0; mt < 4; ++mt) {
      const f32x4 ah = cb[((ww * 2 + 0) * 4 + mt) * 64 + lane];
      const f32x4 al = cb[((ww * 2 + 1) * 4 + mt) * 64 + lane];
#pragma unroll
      for (int g4 = 0; g4 < 4; ++g4) { oh[mt][g4] += ah[g4]; ol[mt][g4] += al[g4]; }
    }
    lsh += lb[(ww * 2 + 0) * 64 + lane];
    lsl += lb[(ww * 2 + 1) * 64 + lane];
    lsh += __shfl_xor(lsh, 16);
    lsh += __shfl_xor(lsh, 32);
    lsl += __shfl_xor(lsl, 16);
    lsl += __shfl_xor(lsl, 32);
    const float invh = 1.f / lsh, invl = 1.f / lsl;
#pragma unroll
    for (int mt = 0; mt < 4; ++mt) {
      const int d0 = mt * 16 + quad * 4;
      short4v ph, pl2;
      *(__hip_bfloat162*)&ph = __float22bfloat162_rn(
          float2{oh[mt][0] * invh, oh[mt][1] * invh});
      *((__hip_bfloat162*)&ph + 1) = __float22bfloat162_rn(
          float2{oh[mt][2] * invh, oh[mt][3] * invh});
      *(short4v*)(Ob + (size_t)(b * 2048 + qrow_hi) * 1024 + h * 64 + d0) = ph;
      *(__hip_bfloat162*)&pl2 = __float22bfloat162_rn(
          float2{ol[mt][0] * invl, ol[mt][1] * invl});
      *((__hip_bfloat162*)&pl2 + 1) = __float22bfloat162_rn(
          float2{ol[mt][2] * invl, ol[mt][3] * invl});
      *(short4v*)(Ob + (size_t)(b * 2048 + qrow_lo) * 1024 + h * 64 + d0) = pl2;
    }
  }
}

extern "C" void kernel_launch(void* const* d_in, const int* in_sizes, int n_in,
                              void* d_out, int out_size, void* d_ws, size_t ws_size,
                              hipStream_t stream) {
  const float* x  = (const float*)d_in[0];
  const float* Wq = (const float*)d_in[1];
  const float* bq = (const float*)d_in[2];
  const float* Wk = (const float*)d_in[3];
  const float* bk = (const float*)d_in[4];
  const float* Wv = (const float*)d_in[5];
  const float* bv = (const float*)d_in[6];
  const float* Wo = (const float*)d_in[7];
  const float* bo = (const float*)d_in[8];
  float* out = (float*)d_out;

  bf16* xb   = (bf16*)d_ws;                     // 4M elems
  bf16* wcat = xb + (size_t)4096 * 1024;        // [wq|wk|wv|wo]
  bf16* wob  = wcat + (size_t)3 * 1024 * 1024;
  bf16* Qb   = wcat + (size_t)4 * 1024 * 1024;
  bf16* Kb   = Qb  + (size_t)4096 * 1024;
  bf16* Vtg  = Kb  + (size_t)4096 * 1024;       // V^T [1024][4096]
  bf16* Ob   = Vtg + (size_t)4096 * 1024;
  const size_t need = ((size_t)4096 * 1024 * 5 + (size_t)1024 * 1024 * 4) * 2;
  if (ws_size < need) return;

  cvt_kernel<<<8192, 256, 0, stream>>>(x, Wq, Wk, Wv, Wo, xb, wcat);
  qkv_kernel<<<dim3(24, 32), 256, 0, stream>>>(xb, wcat, bq, bk, bv,
                                               Qb, Kb, Vtg);
  attn_kernel<<<512, 512, 0, stream>>>(Qb, Kb, Vtg, Ob);
  proj_kernel<<<dim3(8, 64), 256, 0, stream>>>(Ob, wob, bo, out);
}